// Round 1
// baseline (485.329 us; speedup 1.0000x reference)
//
#include <hip/hip_runtime.h>
#include <hip/hip_bf16.h>

#define NNODES 100000
#define HID 128
#define NEDGES 1000000

// ---------------- Kernel 1: node projection GEMM ----------------
// P[m][n] = sum_k emb[m][k] * B[k][n]
//   n <  128 : B[k][n] = W1[k][n]          (W1_top, multiplies h_source)
//   n >= 128 : B[k][n] = W1[128+k][n-128]  (W1_bot, multiplies h_target)
// BM=64, BN=64, BK=16, 256 threads, 4x4 microtile per thread.
__global__ __launch_bounds__(256) void project_kernel(
    const float* __restrict__ emb, const float* __restrict__ W1,
    float* __restrict__ P) {
  __shared__ float As[16][68];  // [k][m], row stride 68 floats (272B, 16B-aligned)
  __shared__ float Bs[16][68];  // [k][n]
  const int t = threadIdx.x;
  const int tx = t & 15;   // n micro index
  const int ty = t >> 4;   // m micro index
  const int m0 = blockIdx.x * 64;
  const int n0 = blockIdx.y * 64;

  float acc[4][4] = {};

  const int a_row = m0 + (t >> 2);   // tile row this thread loads
  const int a_k0  = (t & 3) * 4;     // k offset within chunk
  const int b_k   = t >> 4;          // 0..15
  const int b_n   = (t & 15) * 4;    // 0..60

  for (int k0 = 0; k0 < HID; k0 += 16) {
    float4 a4 = make_float4(0.f, 0.f, 0.f, 0.f);
    if (a_row < NNODES)
      a4 = *(const float4*)(emb + (size_t)a_row * HID + k0 + a_k0);
    const int gk = k0 + b_k;
    const float* brow = (n0 < HID) ? (W1 + (size_t)gk * HID + n0)
                                   : (W1 + (size_t)(HID + gk) * HID + (n0 - HID));
    const float4 b4 = *(const float4*)(brow + b_n);

    __syncthreads();  // previous iteration's LDS reads done
    As[a_k0 + 0][t >> 2] = a4.x;
    As[a_k0 + 1][t >> 2] = a4.y;
    As[a_k0 + 2][t >> 2] = a4.z;
    As[a_k0 + 3][t >> 2] = a4.w;
    *(float4*)&Bs[b_k][b_n] = b4;
    __syncthreads();

#pragma unroll
    for (int kk = 0; kk < 16; ++kk) {
      const float4 av = *(const float4*)&As[kk][ty * 4];
      const float4 bv = *(const float4*)&Bs[kk][tx * 4];
      acc[0][0] += av.x * bv.x; acc[0][1] += av.x * bv.y; acc[0][2] += av.x * bv.z; acc[0][3] += av.x * bv.w;
      acc[1][0] += av.y * bv.x; acc[1][1] += av.y * bv.y; acc[1][2] += av.y * bv.z; acc[1][3] += av.y * bv.w;
      acc[2][0] += av.z * bv.x; acc[2][1] += av.z * bv.y; acc[2][2] += av.z * bv.z; acc[2][3] += av.z * bv.w;
      acc[3][0] += av.w * bv.x; acc[3][1] += av.w * bv.y; acc[3][2] += av.w * bv.z; acc[3][3] += av.w * bv.w;
    }
  }

#pragma unroll
  for (int i = 0; i < 4; ++i) {
    const int row = m0 + ty * 4 + i;
    if (row < NNODES) {
      *(float4*)(P + (size_t)row * 256 + n0 + tx * 4) =
          make_float4(acc[i][0], acc[i][1], acc[i][2], acc[i][3]);
    }
  }
}

// ---------------- Kernel 2: per-edge MLP + exp ----------------
// One wave per edge (grid-stride). Lane l handles hidden cols 2l, 2l+1.
__global__ __launch_bounds__(256) void edge_kernel(
    const float* __restrict__ P, const int* __restrict__ lm,
    const float* __restrict__ b1, const float* __restrict__ W2,
    const float* __restrict__ b2, float* __restrict__ explog,
    float* __restrict__ sum_accum) {
  const int lane = threadIdx.x & 63;
  const int wid  = threadIdx.x >> 6;
  const int gw   = blockIdx.x * 4 + wid;
  const int nw   = gridDim.x * 4;
  const int c    = lane * 2;

  const float2 b1v = *(const float2*)(b1 + c);
  const float2 w2v = *(const float2*)(W2 + c);
  const float  b2v = b2[0];

  float lsum = 0.f;
  for (int e = gw; e < NEDGES; e += nw) {
    const int src = lm[e];
    const int tgt = lm[NEDGES + e];
    const float2 ps = *(const float2*)(P + (size_t)src * 256 + c);
    const float2 pt = *(const float2*)(P + (size_t)tgt * 256 + 128 + c);
    float hx = ps.x + pt.x + b1v.x; hx = hx > 0.f ? hx : 0.f;
    float hy = ps.y + pt.y + b1v.y; hy = hy > 0.f ? hy : 0.f;
    float p = hx * w2v.x + hy * w2v.y;
#pragma unroll
    for (int off = 32; off >= 1; off >>= 1) p += __shfl_xor(p, off, 64);
    const float ev = __expf(p + b2v);
    if (lane == 0) {
      explog[e] = ev;
      lsum += ev;
    }
  }

  __shared__ float wsums[4];
  if (lane == 0) wsums[wid] = lsum;
  __syncthreads();
  if (threadIdx.x == 0)
    atomicAdd(sum_accum, wsums[0] + wsums[1] + wsums[2] + wsums[3]);
}

// ---------------- Kernel 3: normalize ----------------
__global__ __launch_bounds__(256) void norm_kernel(
    const float* __restrict__ explog, const float* __restrict__ sum_accum,
    float* __restrict__ out) {
  const float inv = 1.0f / *sum_accum;
  const int i = (blockIdx.x * 256 + threadIdx.x) * 4;
  if (i < NEDGES) {
    float4 v = *(const float4*)(explog + i);
    v.x *= inv; v.y *= inv; v.z *= inv; v.w *= inv;
    *(float4*)(out + i) = v;
  }
}

extern "C" void kernel_launch(void* const* d_in, const int* in_sizes, int n_in,
                              void* d_out, int out_size, void* d_ws, size_t ws_size,
                              hipStream_t stream) {
  const float* emb = (const float*)d_in[0];
  const int*   lm  = (const int*)d_in[1];   // [2, 1M]: sources then targets
  const float* W1  = (const float*)d_in[2];
  const float* b1  = (const float*)d_in[3];
  const float* W2  = (const float*)d_in[4];
  const float* b2  = (const float*)d_in[5];
  float* out = (float*)d_out;

  char* ws = (char*)d_ws;
  float* P      = (float*)ws;                   // 100000*256*4 = 102,400,000 B
  float* accum  = (float*)(ws + 102400000);     // 256 B
  float* explog = (float*)(ws + 102400256);     // 4,000,000 B

  hipMemsetAsync(accum, 0, 256, stream);

  dim3 g1(1563, 4);  // 1563*64 = 100032 rows, 4*64 = 256 cols
  project_kernel<<<g1, 256, 0, stream>>>(emb, W1, P);
  edge_kernel<<<1024, 256, 0, stream>>>(P, lm, b1, W2, b2, explog, accum);
  norm_kernel<<<977, 256, 0, stream>>>(explog, accum, out);
}

// Round 2
// 280.657 us; speedup vs baseline: 1.7293x; 1.7293x over previous
//
#include <hip/hip_runtime.h>
#include <hip/hip_bf16.h>
#include <hip/hip_fp16.h>

#define NNODES 100000
#define HID 128
#define NEDGES 1000000

// ---------------- Kernel 1: node projection GEMM (fp32 compute, fp16 store) --
// P[m][n] = sum_k emb[m][k] * B[k][n]
//   n <  128 : B[k][n] = W1[k][n]          (W1_top, multiplies h_source)
//   n >= 128 : B[k][n] = W1[128+k][n-128]  (W1_bot, multiplies h_target)
// BM=64, BN=64, BK=16, 256 threads, 4x4 microtile per thread.
__global__ __launch_bounds__(256) void project_kernel(
    const float* __restrict__ emb, const float* __restrict__ W1,
    __half* __restrict__ P) {
  __shared__ float As[16][68];  // [k][m]
  __shared__ float Bs[16][68];  // [k][n]
  const int t = threadIdx.x;
  const int tx = t & 15;   // n micro index
  const int ty = t >> 4;   // m micro index
  const int m0 = blockIdx.x * 64;
  const int n0 = blockIdx.y * 64;

  float acc[4][4] = {};

  const int a_row = m0 + (t >> 2);
  const int a_k0  = (t & 3) * 4;
  const int b_k   = t >> 4;
  const int b_n   = (t & 15) * 4;

  for (int k0 = 0; k0 < HID; k0 += 16) {
    float4 a4 = make_float4(0.f, 0.f, 0.f, 0.f);
    if (a_row < NNODES)
      a4 = *(const float4*)(emb + (size_t)a_row * HID + k0 + a_k0);
    const int gk = k0 + b_k;
    const float* brow = (n0 < HID) ? (W1 + (size_t)gk * HID + n0)
                                   : (W1 + (size_t)(HID + gk) * HID + (n0 - HID));
    const float4 b4 = *(const float4*)(brow + b_n);

    __syncthreads();
    As[a_k0 + 0][t >> 2] = a4.x;
    As[a_k0 + 1][t >> 2] = a4.y;
    As[a_k0 + 2][t >> 2] = a4.z;
    As[a_k0 + 3][t >> 2] = a4.w;
    *(float4*)&Bs[b_k][b_n] = b4;
    __syncthreads();

#pragma unroll
    for (int kk = 0; kk < 16; ++kk) {
      const float4 av = *(const float4*)&As[kk][ty * 4];
      const float4 bv = *(const float4*)&Bs[kk][tx * 4];
      acc[0][0] += av.x * bv.x; acc[0][1] += av.x * bv.y; acc[0][2] += av.x * bv.z; acc[0][3] += av.x * bv.w;
      acc[1][0] += av.y * bv.x; acc[1][1] += av.y * bv.y; acc[1][2] += av.y * bv.z; acc[1][3] += av.y * bv.w;
      acc[2][0] += av.z * bv.x; acc[2][1] += av.z * bv.y; acc[2][2] += av.z * bv.z; acc[2][3] += av.z * bv.w;
      acc[3][0] += av.w * bv.x; acc[3][1] += av.w * bv.y; acc[3][2] += av.w * bv.z; acc[3][3] += av.w * bv.w;
    }
  }

#pragma unroll
  for (int i = 0; i < 4; ++i) {
    const int row = m0 + ty * 4 + i;
    if (row < NNODES) {
      union { __half2 h[2]; uint2 u; } pk;
      pk.h[0] = __floats2half2_rn(acc[i][0], acc[i][1]);
      pk.h[1] = __floats2half2_rn(acc[i][2], acc[i][3]);
      *(uint2*)(P + (size_t)row * 256 + n0 + tx * 4) = pk.u;
    }
  }
}

// ---------------- Kernel 2: per-edge MLP + exp (fp16 gather, x4 unroll) -----
// One wave per 4 consecutive edges (grid-stride). Lane l handles cols 2l,2l+1.
__global__ __launch_bounds__(256) void edge_kernel(
    const __half* __restrict__ P, const int* __restrict__ lm,
    const float* __restrict__ b1, const float* __restrict__ W2,
    const float* __restrict__ b2, float* __restrict__ explog,
    float* __restrict__ sum_accum) {
  const int lane = threadIdx.x & 63;
  const int wid  = threadIdx.x >> 6;
  const int gw   = blockIdx.x * 4 + wid;
  const int nw   = gridDim.x * 4;
  const int c    = lane * 2;

  const float2 b1v = *(const float2*)(b1 + c);
  const float2 w2v = *(const float2*)(W2 + c);
  const float  b2v = b2[0];

  float lsum = 0.f;
  for (int e0 = gw * 4; e0 < NEDGES; e0 += nw * 4) {
    const int n_e = NEDGES - e0;  // >=1 here
    __half2 rs[4], rt[4];
    // issue all gathers before any use
#pragma unroll
    for (int j = 0; j < 4; ++j) {
      const int ej = (j < n_e) ? (e0 + j) : e0;
      const int src = lm[ej];
      const int tgt = lm[NEDGES + ej];
      rs[j] = *(const __half2*)(P + (size_t)src * 256 + c);
      rt[j] = *(const __half2*)(P + (size_t)tgt * 256 + 128 + c);
    }
#pragma unroll
    for (int j = 0; j < 4; ++j) {
      const float2 ps = __half22float2(rs[j]);
      const float2 pt = __half22float2(rt[j]);
      float hx = ps.x + pt.x + b1v.x; hx = hx > 0.f ? hx : 0.f;
      float hy = ps.y + pt.y + b1v.y; hy = hy > 0.f ? hy : 0.f;
      float p = hx * w2v.x + hy * w2v.y;
#pragma unroll
      for (int off = 32; off >= 1; off >>= 1) p += __shfl_xor(p, off, 64);
      if (lane == j && j < n_e) {
        const float ev = __expf(p + b2v);
        explog[e0 + j] = ev;
        lsum += ev;
      }
    }
  }

  // wave reduce lsum, then block reduce, one atomic per block
#pragma unroll
  for (int off = 32; off >= 1; off >>= 1) lsum += __shfl_xor(lsum, off, 64);
  __shared__ float wsums[4];
  if (lane == 0) wsums[wid] = lsum;
  __syncthreads();
  if (threadIdx.x == 0)
    atomicAdd(sum_accum, wsums[0] + wsums[1] + wsums[2] + wsums[3]);
}

// ---------------- Kernel 3: normalize ----------------
__global__ __launch_bounds__(256) void norm_kernel(
    const float* __restrict__ explog, const float* __restrict__ sum_accum,
    float* __restrict__ out) {
  const float inv = 1.0f / *sum_accum;
  const int i = (blockIdx.x * 256 + threadIdx.x) * 4;
  if (i < NEDGES) {
    float4 v = *(const float4*)(explog + i);
    v.x *= inv; v.y *= inv; v.z *= inv; v.w *= inv;
    *(float4*)(out + i) = v;
  }
}

extern "C" void kernel_launch(void* const* d_in, const int* in_sizes, int n_in,
                              void* d_out, int out_size, void* d_ws, size_t ws_size,
                              hipStream_t stream) {
  const float* emb = (const float*)d_in[0];
  const int*   lm  = (const int*)d_in[1];   // [2, 1M]: sources then targets
  const float* W1  = (const float*)d_in[2];
  const float* b1  = (const float*)d_in[3];
  const float* W2  = (const float*)d_in[4];
  const float* b2  = (const float*)d_in[5];
  float* out = (float*)d_out;

  char* ws = (char*)d_ws;
  __half* P     = (__half*)ws;                 // 100000*256*2 = 51,200,000 B
  float* accum  = (float*)(ws + 51200000);     // 256 B
  float* explog = (float*)(ws + 51200256);     // 4,000,000 B

  hipMemsetAsync(accum, 0, 256, stream);

  dim3 g1(1563, 4);  // 1563*64 = 100032 rows, 4*64 = 256 cols
  project_kernel<<<g1, 256, 0, stream>>>(emb, W1, P);
  edge_kernel<<<2048, 256, 0, stream>>>(P, lm, b1, W2, b2, explog, accum);
  norm_kernel<<<977, 256, 0, stream>>>(explog, accum, out);
}

// Round 4
// 207.183 us; speedup vs baseline: 2.3425x; 1.3546x over previous
//
#include <hip/hip_runtime.h>
#include <hip/hip_bf16.h>
#include <hip/hip_fp16.h>
#include <stdint.h>

#define NNODES 100000
#define HID 128
#define NEDGES 1000000

typedef __attribute__((ext_vector_type(8))) short short8;
typedef __attribute__((ext_vector_type(4))) float floatx4;
typedef _Float16 f16x2 __attribute__((ext_vector_type(2)));

__device__ __forceinline__ unsigned short bf16_rn(float x) {
  unsigned u = __builtin_bit_cast(unsigned, x);
  u += 0x7fffu + ((u >> 16) & 1u);
  return (unsigned short)(u >> 16);
}
__device__ __forceinline__ float bf16_to_f(unsigned short h) {
  unsigned u = ((unsigned)h) << 16;
  return __builtin_bit_cast(float, u);
}

// ---------------- Kernel 0: pack B = [W1_top | W1_bot] into MFMA fragment
// order, bf16 hi/lo split. Fragment (verified): B[k=(lane>>4)*8+j][n=lane&15].
// Element base = ((ct*4 + ks)*64 + lane)*8, ct=0..15 (16-col tiles), ks=0..3.
__global__ __launch_bounds__(256) void pack_b_kernel(
    const float* __restrict__ W1, short* __restrict__ Bhi,
    short* __restrict__ Blo) {
  const int t = blockIdx.x * 256 + threadIdx.x;  // 0..4095
  const int lane = t & 63;
  const int ks = (t >> 6) & 3;
  const int ct = t >> 8;
  const int n = ct * 16 + (lane & 15);
  const int kb = ks * 32 + ((lane >> 4) * 8);
  short8 h, l;
#pragma unroll
  for (int j = 0; j < 8; ++j) {
    const int k = kb + j;
    const float v = (n < HID) ? W1[(size_t)k * HID + n]
                              : W1[(size_t)(HID + k) * HID + (n - HID)];
    const unsigned short hh = bf16_rn(v);
    h[j] = (short)hh;
    l[j] = (short)bf16_rn(v - bf16_to_f(hh));
  }
  *(short8*)(Bhi + (size_t)t * 8) = h;
  *(short8*)(Blo + (size_t)t * 8) = l;
}

// ---------------- Kernel 1: node projection via MFMA (bf16 hi/lo split) ----
// Block: 64 rows x 256 cols (full N -> emb read exactly once).
// 4 waves; wave w owns cols [64w, 64w+64) = 4 col-tiles; 4 row-tiles of 16.
// P[m][n] = emb[m][:] @ B[:][n], fp16 store.
__global__ __launch_bounds__(256) void project_kernel(
    const float* __restrict__ emb, const short* __restrict__ Bhi,
    const short* __restrict__ Blo, __half* __restrict__ P) {
  __shared__ short Ahi[64 * 40];   // [row][k 0..31], row stride 40 shorts (pad)
  __shared__ short Alo[64 * 40];
  __shared__ __half Co[64 * 264];  // output staging, row stride 264 halfs

  const int t = threadIdx.x;
  const int lane = t & 63;
  const int w = t >> 6;
  const int l16 = lane & 15;
  const int q = lane >> 4;
  const int row0 = blockIdx.x * 64;

  floatx4 acc[4][4] = {};  // [rt][ct]

  // cooperative A staging: thread t loads row ar, k-chunk ak (8 fp32)
  const int ar = t >> 2;
  const int ak = (t & 3) * 8;
  const bool arow_ok = (row0 + ar) < NNODES;
  const float* aptr = emb + (size_t)(row0 + ar) * HID + ak;

#pragma unroll
  for (int ks = 0; ks < 4; ++ks) {
    // B fragments straight from pre-packed global (L1/L2-hot)
    short8 bh[4], bl[4];
#pragma unroll
    for (int ct = 0; ct < 4; ++ct) {
      const size_t idx = (size_t)((((w * 4 + ct) * 4 + ks) * 64 + lane)) * 8;
      bh[ct] = *(const short8*)(Bhi + idx);
      bl[ct] = *(const short8*)(Blo + idx);
    }
    // A global load (8 fp32)
    float x[8];
    if (arow_ok) {
      const floatx4 v0 = *(const floatx4*)(aptr + ks * 32);
      const floatx4 v1 = *(const floatx4*)(aptr + ks * 32 + 4);
      x[0] = v0.x; x[1] = v0.y; x[2] = v0.z; x[3] = v0.w;
      x[4] = v1.x; x[5] = v1.y; x[6] = v1.z; x[7] = v1.w;
    } else {
#pragma unroll
      for (int j = 0; j < 8; ++j) x[j] = 0.f;
    }
    __syncthreads();  // previous iteration's fragment reads complete
    short8 h8, l8;
#pragma unroll
    for (int j = 0; j < 8; ++j) {
      const unsigned short hh = bf16_rn(x[j]);
      h8[j] = (short)hh;
      l8[j] = (short)bf16_rn(x[j] - bf16_to_f(hh));
    }
    *(short8*)&Ahi[ar * 40 + ak] = h8;
    *(short8*)&Alo[ar * 40 + ak] = l8;
    __syncthreads();

#pragma unroll
    for (int rt = 0; rt < 4; ++rt) {
      const int la = (rt * 16 + l16) * 40 + q * 8;
      const short8 ah = *(const short8*)&Ahi[la];
      const short8 al = *(const short8*)&Alo[la];
#pragma unroll
      for (int ct = 0; ct < 4; ++ct) {
        acc[rt][ct] = __builtin_amdgcn_mfma_f32_16x16x32_bf16(ah, bh[ct], acc[rt][ct], 0, 0, 0);
        acc[rt][ct] = __builtin_amdgcn_mfma_f32_16x16x32_bf16(al, bh[ct], acc[rt][ct], 0, 0, 0);
        acc[rt][ct] = __builtin_amdgcn_mfma_f32_16x16x32_bf16(ah, bl[ct], acc[rt][ct], 0, 0, 0);
      }
    }
  }

  // epilogue: C/D layout col=lane&15, row=(lane>>4)*4+reg -> LDS -> coalesced
  __syncthreads();
#pragma unroll
  for (int rt = 0; rt < 4; ++rt)
#pragma unroll
    for (int ct = 0; ct < 4; ++ct)
#pragma unroll
      for (int r = 0; r < 4; ++r) {
        const int row = rt * 16 + q * 4 + r;
        const int col = w * 64 + ct * 16 + l16;
        Co[row * 264 + col] = __float2half(acc[rt][ct][r]);
      }
  __syncthreads();
#pragma unroll
  for (int i = 0; i < 8; ++i) {
    const int chunk = t + i * 256;  // 2048 chunks of 16B, 32 per row
    const int row = chunk >> 5;
    const int cx = chunk & 31;
    if (row0 + row < NNODES) {
      const floatx4 v = *(const floatx4*)&Co[row * 264 + cx * 8];
      *(floatx4*)(P + (size_t)(row0 + row) * 256 + cx * 8) = v;
    }
  }
}

// ---------------- Kernel 2: per-edge MLP + exp --------------------
// Wave = 2 x 32-lane halves; each half owns one edge, lane handles 4 hidden
// cols (c = (lane&31)*4). 4 pair-iterations unrolled -> 8 edges/wave/iter,
// 16 outstanding 8B gathers. Packed-half math + v_dot2_f32_f16.
__global__ __launch_bounds__(256) void edge_kernel(
    const __half* __restrict__ P, const int* __restrict__ lm,
    const float* __restrict__ b1, const float* __restrict__ W2,
    const float* __restrict__ b2, float* __restrict__ explog,
    float* __restrict__ sum_accum) {
  const int lane = threadIdx.x & 63;
  const int wid = threadIdx.x >> 6;
  const int sub = lane >> 5;
  const int l32 = lane & 31;
  const int c = l32 * 4;

  const floatx4 b1v = *(const floatx4*)(b1 + c);
  const floatx4 w2v = *(const floatx4*)(W2 + c);
  const f16x2 b1a = {(_Float16)b1v.x, (_Float16)b1v.y};
  const f16x2 b1b = {(_Float16)b1v.z, (_Float16)b1v.w};
  const f16x2 w2a = {(_Float16)w2v.x, (_Float16)w2v.y};
  const f16x2 w2b = {(_Float16)w2v.z, (_Float16)w2v.w};
  const f16x2 z2 = {(_Float16)0.f, (_Float16)0.f};
  const float b2v = b2[0];

  const int gw = blockIdx.x * 4 + wid;
  const int nw = gridDim.x * 4;

  float lsum = 0.f;
  for (int e0 = gw * 8; e0 < NEDGES; e0 += nw * 8) {
    uint2 rs[4], rt_[4];
#pragma unroll
    for (int j = 0; j < 4; ++j) {
      int ej = e0 + j * 2 + sub;
      if (ej >= NEDGES) ej = e0;
      const int src = lm[ej];
      const int tgt = lm[NEDGES + ej];
      rs[j]  = *(const uint2*)(P + (size_t)src * 256 + c);
      rt_[j] = *(const uint2*)(P + (size_t)tgt * 256 + 128 + c);
    }
#pragma unroll
    for (int j = 0; j < 4; ++j) {
      const f16x2 sa = __builtin_bit_cast(f16x2, rs[j].x);
      const f16x2 sb = __builtin_bit_cast(f16x2, rs[j].y);
      const f16x2 ta = __builtin_bit_cast(f16x2, rt_[j].x);
      const f16x2 tb = __builtin_bit_cast(f16x2, rt_[j].y);
      const f16x2 ha = __builtin_elementwise_max(sa + ta + b1a, z2);
      const f16x2 hb = __builtin_elementwise_max(sb + tb + b1b, z2);
      float p = __builtin_amdgcn_fdot2(
          ha, w2a, __builtin_amdgcn_fdot2(hb, w2b, 0.f, false), false);
#pragma unroll
      for (int off = 16; off >= 1; off >>= 1) p += __shfl_xor(p, off, 64);
      if (l32 == j) {
        const int ej = e0 + j * 2 + sub;
        if (ej < NEDGES) {
          const float ev = __expf(p + b2v);
          explog[ej] = ev;
          lsum += ev;
        }
      }
    }
  }

#pragma unroll
  for (int off = 32; off >= 1; off >>= 1) lsum += __shfl_xor(lsum, off, 64);
  __shared__ float wsums[4];
  if (lane == 0) wsums[wid] = lsum;
  __syncthreads();
  if (threadIdx.x == 0)
    atomicAdd(sum_accum, wsums[0] + wsums[1] + wsums[2] + wsums[3]);
}

// ---------------- Kernel 3: normalize ----------------
__global__ __launch_bounds__(256) void norm_kernel(
    const float* __restrict__ explog, const float* __restrict__ sum_accum,
    float* __restrict__ out) {
  const float inv = 1.0f / *sum_accum;
  const int i = (blockIdx.x * 256 + threadIdx.x) * 4;
  if (i < NEDGES) {
    floatx4 v = *(const floatx4*)(explog + i);
    v.x *= inv; v.y *= inv; v.z *= inv; v.w *= inv;
    *(floatx4*)(out + i) = v;
  }
}

extern "C" void kernel_launch(void* const* d_in, const int* in_sizes, int n_in,
                              void* d_out, int out_size, void* d_ws, size_t ws_size,
                              hipStream_t stream) {
  const float* emb = (const float*)d_in[0];
  const int*   lm  = (const int*)d_in[1];   // [2, 1M]: sources then targets
  const float* W1  = (const float*)d_in[2];
  const float* b1  = (const float*)d_in[3];
  const float* W2  = (const float*)d_in[4];
  const float* b2  = (const float*)d_in[5];
  float* out = (float*)d_out;

  char* ws = (char*)d_ws;
  __half* P     = (__half*)ws;                   // 51,200,000 B
  float* accum  = (float*)(ws + 51200000);       // 256 B
  float* explog = (float*)(ws + 51200256);       // 4,000,000 B
  short* Bhi    = (short*)(ws + 55200256);       // 65,536 B
  short* Blo    = (short*)(ws + 55265792);       // 65,536 B

  (void)hipMemsetAsync(accum, 0, 256, stream);

  pack_b_kernel<<<16, 256, 0, stream>>>(W1, Bhi, Blo);
  project_kernel<<<1563, 256, 0, stream>>>(emb, Bhi, Blo, P);  // 1563*64 >= 100000
  edge_kernel<<<2048, 256, 0, stream>>>(P, lm, b1, W2, b2, explog, accum);
  norm_kernel<<<977, 256, 0, stream>>>(explog, accum, out);
}

// Round 5
// 196.411 us; speedup vs baseline: 2.4710x; 1.0548x over previous
//
#include <hip/hip_runtime.h>
#include <hip/hip_bf16.h>
#include <hip/hip_fp16.h>
#include <stdint.h>

#define NNODES 100000
#define HID 128
#define NEDGES 1000000

typedef __attribute__((ext_vector_type(8))) short short8;
typedef __attribute__((ext_vector_type(4))) float floatx4;
typedef _Float16 f16x2 __attribute__((ext_vector_type(2)));

__device__ __forceinline__ unsigned short bf16_rn(float x) {
  unsigned u = __builtin_bit_cast(unsigned, x);
  u += 0x7fffu + ((u >> 16) & 1u);
  return (unsigned short)(u >> 16);
}
__device__ __forceinline__ float bf16_to_f(unsigned short h) {
  unsigned u = ((unsigned)h) << 16;
  return __builtin_bit_cast(float, u);
}

// ---------------- Kernel 0: pack B = [W1_top | W1_bot] into MFMA fragment
// order, bf16 hi/lo split. Fragment: B[k=(lane>>4)*8+j][n=lane&15].
// Element base = ((ct*4 + ks)*64 + lane)*8, ct=0..15 (16-col tiles), ks=0..3.
__global__ __launch_bounds__(256) void pack_b_kernel(
    const float* __restrict__ W1, short* __restrict__ Bhi,
    short* __restrict__ Blo) {
  const int t = blockIdx.x * 256 + threadIdx.x;  // 0..4095
  const int lane = t & 63;
  const int ks = (t >> 6) & 3;
  const int ct = t >> 8;
  const int n = ct * 16 + (lane & 15);
  const int kb = ks * 32 + ((lane >> 4) * 8);
  short8 h, l;
#pragma unroll
  for (int j = 0; j < 8; ++j) {
    const int k = kb + j;
    const float v = (n < HID) ? W1[(size_t)k * HID + n]
                              : W1[(size_t)(HID + k) * HID + (n - HID)];
    const unsigned short hh = bf16_rn(v);
    h[j] = (short)hh;
    l[j] = (short)bf16_rn(v - bf16_to_f(hh));
  }
  *(short8*)(Bhi + (size_t)t * 8) = h;
  *(short8*)(Blo + (size_t)t * 8) = l;
}

// ---------------- Kernel 1: node projection via MFMA (bf16 hi/lo split) ----
// Block: 64 rows x 256 cols. Stage ALL of A into LDS up front (hi/lo bf16),
// ONE barrier, then barrier-free K-loop with double-buffered B fragments.
// P[m][n] = emb[m][:] @ B[:][n], fp16 store. Epilogue aliases Co onto A LDS.
__global__ __launch_bounds__(256) void project_kernel(
    const float* __restrict__ emb, const short* __restrict__ Bhi,
    const short* __restrict__ Blo, __half* __restrict__ P) {
  __shared__ __align__(16) char smem[34816];
  short* Ahi = (short*)smem;            // 64 rows x 136 shorts = 17408 B
  short* Alo = (short*)(smem + 17408);  // 17408 B
  __half* Co = (__half*)smem;           // alias, 64 x 264 halfs = 33792 B

  const int t = threadIdx.x;
  const int lane = t & 63;
  const int w = t >> 6;
  const int l16 = lane & 15;
  const int q = lane >> 4;
  const int row0 = blockIdx.x * 64;

  // ---- stage all A: thread t loads row t>>2, k-chunk (t&3)*32 (32 fp32) ----
  {
    const int ar = t >> 2;
    const int kb = (t & 3) * 32;
    const bool ok = (row0 + ar) < NNODES;
    const float* aptr = emb + (size_t)(row0 + ar) * HID + kb;
    float x[32];
    if (ok) {
#pragma unroll
      for (int j = 0; j < 8; ++j) {
        const floatx4 v = *(const floatx4*)(aptr + j * 4);
        x[j * 4 + 0] = v.x; x[j * 4 + 1] = v.y;
        x[j * 4 + 2] = v.z; x[j * 4 + 3] = v.w;
      }
    } else {
#pragma unroll
      for (int j = 0; j < 32; ++j) x[j] = 0.f;
    }
    short8 h8[4], l8[4];
#pragma unroll
    for (int j = 0; j < 32; ++j) {
      const unsigned short hh = bf16_rn(x[j]);
      h8[j >> 3][j & 7] = (short)hh;
      l8[j >> 3][j & 7] = (short)bf16_rn(x[j] - bf16_to_f(hh));
    }
    const int base = ar * 136 + kb;
#pragma unroll
    for (int j = 0; j < 4; ++j) {
      *(short8*)&Ahi[base + j * 8] = h8[j];
      *(short8*)&Alo[base + j * 8] = l8[j];
    }
  }
  __syncthreads();  // the only barrier before the K-loop

  floatx4 acc[4][4] = {};  // [rt][ct]
  short8 bh[2][4], bl[2][4];
#pragma unroll
  for (int ct = 0; ct < 4; ++ct) {
    const size_t idx = (size_t)(((w * 4 + ct) * 4 + 0) * 64 + lane) * 8;
    bh[0][ct] = *(const short8*)(Bhi + idx);
    bl[0][ct] = *(const short8*)(Blo + idx);
  }

#pragma unroll
  for (int ks = 0; ks < 4; ++ks) {
    const int cur = ks & 1;
    if (ks < 3) {  // prefetch next B fragments during this step's MFMAs
#pragma unroll
      for (int ct = 0; ct < 4; ++ct) {
        const size_t idx =
            (size_t)(((w * 4 + ct) * 4 + (ks + 1)) * 64 + lane) * 8;
        bh[cur ^ 1][ct] = *(const short8*)(Bhi + idx);
        bl[cur ^ 1][ct] = *(const short8*)(Blo + idx);
      }
    }
#pragma unroll
    for (int rt = 0; rt < 4; ++rt) {
      const int la = (rt * 16 + l16) * 136 + ks * 32 + q * 8;
      const short8 ah = *(const short8*)&Ahi[la];
      const short8 al = *(const short8*)&Alo[la];
#pragma unroll
      for (int ct = 0; ct < 4; ++ct) {
        acc[rt][ct] = __builtin_amdgcn_mfma_f32_16x16x32_bf16(ah, bh[cur][ct], acc[rt][ct], 0, 0, 0);
        acc[rt][ct] = __builtin_amdgcn_mfma_f32_16x16x32_bf16(al, bh[cur][ct], acc[rt][ct], 0, 0, 0);
        acc[rt][ct] = __builtin_amdgcn_mfma_f32_16x16x32_bf16(ah, bl[cur][ct], acc[rt][ct], 0, 0, 0);
      }
    }
  }

  // epilogue: C/D layout col=lane&15, row=(lane>>4)*4+reg -> LDS -> coalesced
  __syncthreads();  // A reads done; safe to alias Co
#pragma unroll
  for (int rt = 0; rt < 4; ++rt)
#pragma unroll
    for (int ct = 0; ct < 4; ++ct)
#pragma unroll
      for (int r = 0; r < 4; ++r) {
        const int row = rt * 16 + q * 4 + r;
        const int col = w * 64 + ct * 16 + l16;
        Co[row * 264 + col] = __float2half(acc[rt][ct][r]);
      }
  __syncthreads();
#pragma unroll
  for (int i = 0; i < 8; ++i) {
    const int chunk = t + i * 256;  // 2048 chunks of 16B, 32 per row
    const int row = chunk >> 5;
    const int cx = chunk & 31;
    if (row0 + row < NNODES) {
      const floatx4 v = *(const floatx4*)&Co[row * 264 + cx * 8];
      *(floatx4*)(P + (size_t)(row0 + row) * 256 + cx * 8) = v;
    }
  }
}

// ---------------- Kernel 2: per-edge MLP + exp --------------------
// 16 lanes per edge: lane covers 8 hidden cols (one dwordx4 gather each for
// src/tgt halves). Wave = 4 edge-groups; 4 j-steps unrolled -> 16 edges/iter,
// 8 outstanding 16B gathers/lane. Packed-half math + v_dot2_f32_f16,
// 4-shuffle reduce per 4 edges.
__global__ __launch_bounds__(256) void edge_kernel(
    const __half* __restrict__ P, const int* __restrict__ lm,
    const float* __restrict__ b1, const float* __restrict__ W2,
    const float* __restrict__ b2, float* __restrict__ explog,
    float* __restrict__ sum_accum) {
  const int lane = threadIdx.x & 63;
  const int wid = threadIdx.x >> 6;
  const int g = lane >> 4;    // edge sub-group 0..3
  const int l16 = lane & 15;
  const int c = l16 * 8;      // 8 halfs per lane

  f16x2 b1h[4], w2h[4];
  {
    const floatx4 b1a = *(const floatx4*)(b1 + c);
    const floatx4 b1b = *(const floatx4*)(b1 + c + 4);
    const floatx4 w2a = *(const floatx4*)(W2 + c);
    const floatx4 w2b = *(const floatx4*)(W2 + c + 4);
    b1h[0] = f16x2{(_Float16)b1a.x, (_Float16)b1a.y};
    b1h[1] = f16x2{(_Float16)b1a.z, (_Float16)b1a.w};
    b1h[2] = f16x2{(_Float16)b1b.x, (_Float16)b1b.y};
    b1h[3] = f16x2{(_Float16)b1b.z, (_Float16)b1b.w};
    w2h[0] = f16x2{(_Float16)w2a.x, (_Float16)w2a.y};
    w2h[1] = f16x2{(_Float16)w2a.z, (_Float16)w2a.w};
    w2h[2] = f16x2{(_Float16)w2b.x, (_Float16)w2b.y};
    w2h[3] = f16x2{(_Float16)w2b.z, (_Float16)w2b.w};
  }
  const f16x2 z2 = {(_Float16)0.f, (_Float16)0.f};
  const float b2v = b2[0];

  const int gw = blockIdx.x * 4 + wid;
  const int nw = gridDim.x * 4;

  float lsum = 0.f;
  for (int e0 = gw * 16; e0 < NEDGES; e0 += nw * 16) {
    uint4 rs[4], rt_[4];
#pragma unroll
    for (int j = 0; j < 4; ++j) {
      int ej = e0 + j * 4 + g;
      if (ej >= NEDGES) ej = e0;
      const int src = lm[ej];
      const int tgt = lm[NEDGES + ej];
      rs[j]  = *(const uint4*)(P + (size_t)src * 256 + c);
      rt_[j] = *(const uint4*)(P + (size_t)tgt * 256 + 128 + c);
    }
#pragma unroll
    for (int j = 0; j < 4; ++j) {
      float p = 0.f;
      const unsigned su[4] = {rs[j].x, rs[j].y, rs[j].z, rs[j].w};
      const unsigned tu[4] = {rt_[j].x, rt_[j].y, rt_[j].z, rt_[j].w};
#pragma unroll
      for (int h = 0; h < 4; ++h) {
        const f16x2 s = __builtin_bit_cast(f16x2, su[h]);
        const f16x2 tt = __builtin_bit_cast(f16x2, tu[h]);
        const f16x2 a = __builtin_elementwise_max(s + tt + b1h[h], z2);
        p = __builtin_amdgcn_fdot2(a, w2h[h], p, false);
      }
      p += __shfl_xor(p, 8, 64);
      p += __shfl_xor(p, 4, 64);
      p += __shfl_xor(p, 2, 64);
      p += __shfl_xor(p, 1, 64);
      if (l16 == j) {
        const int ej = e0 + j * 4 + g;
        if (ej < NEDGES) {
          const float ev = __expf(p + b2v);
          explog[ej] = ev;
          lsum += ev;
        }
      }
    }
  }

#pragma unroll
  for (int off = 32; off >= 1; off >>= 1) lsum += __shfl_xor(lsum, off, 64);
  __shared__ float wsums[4];
  if (lane == 0) wsums[wid] = lsum;
  __syncthreads();
  if (threadIdx.x == 0)
    atomicAdd(sum_accum, wsums[0] + wsums[1] + wsums[2] + wsums[3]);
}

// ---------------- Kernel 3: normalize ----------------
__global__ __launch_bounds__(256) void norm_kernel(
    const float* __restrict__ explog, const float* __restrict__ sum_accum,
    float* __restrict__ out) {
  const float inv = 1.0f / *sum_accum;
  const int i = (blockIdx.x * 256 + threadIdx.x) * 4;
  if (i < NEDGES) {
    floatx4 v = *(const floatx4*)(explog + i);
    v.x *= inv; v.y *= inv; v.z *= inv; v.w *= inv;
    *(floatx4*)(out + i) = v;
  }
}

extern "C" void kernel_launch(void* const* d_in, const int* in_sizes, int n_in,
                              void* d_out, int out_size, void* d_ws, size_t ws_size,
                              hipStream_t stream) {
  const float* emb = (const float*)d_in[0];
  const int*   lm  = (const int*)d_in[1];   // [2, 1M]: sources then targets
  const float* W1  = (const float*)d_in[2];
  const float* b1  = (const float*)d_in[3];
  const float* W2  = (const float*)d_in[4];
  const float* b2  = (const float*)d_in[5];
  float* out = (float*)d_out;

  char* ws = (char*)d_ws;
  __half* P     = (__half*)ws;                   // 51,200,000 B
  float* accum  = (float*)(ws + 51200000);       // 256 B
  float* explog = (float*)(ws + 51200256);       // 4,000,000 B
  short* Bhi    = (short*)(ws + 55200256);       // 65,536 B
  short* Blo    = (short*)(ws + 55265792);       // 65,536 B

  (void)hipMemsetAsync(accum, 0, 256, stream);

  pack_b_kernel<<<16, 256, 0, stream>>>(W1, Bhi, Blo);
  project_kernel<<<1563, 256, 0, stream>>>(emb, Bhi, Blo, P);  // 1563*64 >= 100000
  edge_kernel<<<2048, 256, 0, stream>>>(P, lm, b1, W2, b2, explog, accum);
  norm_kernel<<<977, 256, 0, stream>>>(explog, accum, out);
}